// Round 1
// baseline (1031.215 us; speedup 1.0000x reference)
//
#include <hip/hip_runtime.h>
#include <math.h>

#define DIM 64
#define HEADS 8
#define HIDDEN 256

// ---------------- prep: fold linear chains into combined weights ----------------
// Waug[64][80] = [w_in | w_in@w_att_u | w_in@w_att_v], baug[80] matching biases.
// wcc[2][8] = w_edge@w_att_e, bcc[8] = b_edge@w_att_e + b_att_e.
// w1t[256][64] = transpose(w_ff1) for contiguous per-hidden rows.
__global__ void prep_kernel(
    const float* __restrict__ w_in, const float* __restrict__ b_in,
    const float* __restrict__ w_edge, const float* __restrict__ b_edge,
    const float* __restrict__ w_att_u, const float* __restrict__ b_att_u,
    const float* __restrict__ w_att_v,
    const float* __restrict__ w_att_e, const float* __restrict__ b_att_e,
    const float* __restrict__ w_ff1,
    float* __restrict__ Waug, float* __restrict__ baug,
    float* __restrict__ wcc, float* __restrict__ bcc,
    float* __restrict__ w1t)
{
  int t = threadIdx.x; // 256 threads
  if (t < 64) {
    for (int j = 0; j < 64; ++j) Waug[t*80 + j] = w_in[t*64 + j];
    for (int hh = 0; hh < 8; ++hh) {
      float a = 0.f, b = 0.f;
      for (int j = 0; j < 64; ++j) {
        float w = w_in[t*64 + j];
        a += w * w_att_u[j*8 + hh];
        b += w * w_att_v[j*8 + hh];
      }
      Waug[t*80 + 64 + hh] = a;
      Waug[t*80 + 72 + hh] = b;
    }
  } else if (t < 128) {
    int j = t - 64;
    baug[j] = b_in[j];
  } else if (t < 136) {
    int hh = t - 128;
    float a = b_att_u[hh];
    for (int k = 0; k < 64; ++k) a += b_in[k] * w_att_u[k*8 + hh];
    baug[64 + hh] = a;
  } else if (t < 144) {
    int hh = t - 136;
    float a = 0.f;
    for (int k = 0; k < 64; ++k) a += b_in[k] * w_att_v[k*8 + hh];
    baug[72 + hh] = a;
  } else if (t < 160) {
    int c = (t - 144) >> 3, hh = (t - 144) & 7;
    float a = 0.f;
    for (int j = 0; j < 64; ++j) a += w_edge[c*64 + j] * w_att_e[j*8 + hh];
    wcc[c*8 + hh] = a;
  } else if (t < 168) {
    int hh = t - 160;
    float a = b_att_e[hh];
    for (int j = 0; j < 64; ++j) a += b_edge[j] * w_att_e[j*8 + hh];
    bcc[hh] = a;
  }
  // all 256 threads: transpose w_ff1 [64][256] -> w1t [256][64]
  for (int k = 0; k < 64; ++k) w1t[t*64 + k] = w_ff1[k*256 + t];
}

// ---------------- node GEMM: [N,64] @ [64,80] -> h, su, sv ----------------
__global__ __launch_bounds__(256) void node_gemm_kernel(
    const float* __restrict__ x,
    const float* __restrict__ Waug, const float* __restrict__ baug,
    float* __restrict__ hbuf, float* __restrict__ subuf, float* __restrict__ svbuf,
    int n_nodes)
{
  long n = (long)blockIdx.x * blockDim.x + threadIdx.x;
  if (n >= n_nodes) return;
  float xr[64];
  const float4* xp = (const float4*)(x + n*DIM);
  #pragma unroll
  for (int q = 0; q < 16; ++q) {
    float4 v = xp[q];
    xr[4*q] = v.x; xr[4*q+1] = v.y; xr[4*q+2] = v.z; xr[4*q+3] = v.w;
  }
  float acc[80];
  const float4* bp = (const float4*)baug;
  #pragma unroll
  for (int q = 0; q < 20; ++q) {
    float4 v = bp[q];
    acc[4*q] = v.x; acc[4*q+1] = v.y; acc[4*q+2] = v.z; acc[4*q+3] = v.w;
  }
  for (int k = 0; k < 64; ++k) {
    float xv = xr[k];
    const float4* wrow = (const float4*)(Waug + k*80);  // wave-uniform address
    #pragma unroll
    for (int q = 0; q < 20; ++q) {
      float4 w = wrow[q];
      acc[4*q]   += xv * w.x;
      acc[4*q+1] += xv * w.y;
      acc[4*q+2] += xv * w.z;
      acc[4*q+3] += xv * w.w;
    }
  }
  float4* hp = (float4*)(hbuf + n*DIM);
  #pragma unroll
  for (int q = 0; q < 16; ++q) hp[q] = make_float4(acc[4*q], acc[4*q+1], acc[4*q+2], acc[4*q+3]);
  float4* sup = (float4*)(subuf + n*8);
  sup[0] = make_float4(acc[64], acc[65], acc[66], acc[67]);
  sup[1] = make_float4(acc[68], acc[69], acc[70], acc[71]);
  float4* svp = (float4*)(svbuf + n*8);
  svp[0] = make_float4(acc[72], acc[73], acc[74], acc[75]);
  svp[1] = make_float4(acc[76], acc[77], acc[78], acc[79]);
}

// ---------------- CSR build ----------------
__global__ void hist_kernel(const int* __restrict__ dst, int* __restrict__ deg, int n_edges) {
  int i = blockIdx.x * blockDim.x + threadIdx.x;
  if (i < n_edges) atomicAdd(&deg[dst[i]], 1);
}

// per-node contiguous region allocation; order irrelevant -> no global scan needed
__global__ void alloc_kernel(const int* __restrict__ deg, int* __restrict__ off,
                             int* __restrict__ counter, int n_nodes) {
  int i = blockIdx.x * blockDim.x + threadIdx.x;
  int lane = threadIdx.x & 63;
  int d = (i < n_nodes) ? deg[i] : 0;
  int pre = d;
  #pragma unroll
  for (int s = 1; s < 64; s <<= 1) {
    int v = __shfl_up(pre, s, 64);
    if (lane >= s) pre += v;
  }
  int tot = __shfl(pre, 63, 64);
  int base = 0;
  if (lane == 0) base = atomicAdd(counter, tot);
  base = __shfl(base, 0, 64);
  if (i < n_nodes) off[i] = base + pre - d;
}

__global__ void scatter_kernel(const int* __restrict__ dst, const int* __restrict__ off,
                               int* __restrict__ pos, int* __restrict__ csr, int n_edges) {
  int i = blockIdx.x * blockDim.x + threadIdx.x;
  if (i < n_edges) {
    int d = dst[i];
    int p = atomicAdd(&pos[d], 1);
    csr[off[d] + p] = i;
  }
}

// ---------------- attention gather: one wave per dst node ----------------
__device__ __forceinline__ float sel8(float v0, float v1, float v2, float v3,
                                      float v4, float v5, float v6, float v7, int idx) {
  float a0 = (idx & 1) ? v1 : v0;
  float a1 = (idx & 1) ? v3 : v2;
  float a2 = (idx & 1) ? v5 : v4;
  float a3 = (idx & 1) ? v7 : v6;
  float b0 = (idx & 2) ? a1 : a0;
  float b1 = (idx & 2) ? a3 : a2;
  return (idx & 4) ? b1 : b0;
}

__global__ __launch_bounds__(256) void attn_kernel(
    const int* __restrict__ src, const int* __restrict__ csr,
    const int* __restrict__ off, const int* __restrict__ deg,
    const float* __restrict__ edge_feat,
    const float* __restrict__ hbuf, const float* __restrict__ subuf,
    const float* __restrict__ svbuf,
    const float* __restrict__ wcc, const float* __restrict__ bcc,
    float* __restrict__ agg, int n_nodes)
{
  __shared__ float pbuf[4][64][8];
  __shared__ int   sbuf[4][64];
  const int wid = threadIdx.x >> 6;
  const int lane = threadIdx.x & 63;
  const long n = (long)blockIdx.x * 4 + wid;
  if (n >= n_nodes) return;
  const int ebase = off[n];
  const int d = deg[n];
  const int hsel = lane & 7;   // head owning output dim `lane` (h.reshape(n, hd, H))

  float svn[8], c0v[8], c1v[8], cbv[8];
  {
    const float4* svp = (const float4*)(svbuf + n*8);
    float4 s0 = svp[0], s1 = svp[1];
    svn[0]=s0.x; svn[1]=s0.y; svn[2]=s0.z; svn[3]=s0.w;
    svn[4]=s1.x; svn[5]=s1.y; svn[6]=s1.z; svn[7]=s1.w;
    #pragma unroll
    for (int hh = 0; hh < 8; ++hh) {
      c0v[hh] = wcc[hh]; c1v[hh] = wcc[8+hh]; cbv[hh] = bcc[hh];
    }
  }
  float m8[8], den8[8];
  #pragma unroll
  for (int hh = 0; hh < 8; ++hh) { m8[hh] = -INFINITY; den8[hh] = 0.f; }
  float msg = 0.f;

  for (int c0 = 0; c0 < d; c0 += 64) {
    const int cnt = min(64, d - c0);
    float sc[8];
    int sid = 0;
    if (lane < cnt) {
      const int eid = csr[ebase + c0 + lane];
      sid = src[eid];
      const float2 ef = *(const float2*)(edge_feat + (long)eid*2);
      const float4* sup = (const float4*)(subuf + (long)sid*8);
      float4 u0 = sup[0], u1 = sup[1];
      float suv[8] = {u0.x,u0.y,u0.z,u0.w,u1.x,u1.y,u1.z,u1.w};
      #pragma unroll
      for (int hh = 0; hh < 8; ++hh) {
        float v = suv[hh] + svn[hh] + ef.x*c0v[hh] + ef.y*c1v[hh] + cbv[hh];
        sc[hh] = (v > 0.f) ? v : 0.2f*v;   // leaky_relu 0.2
      }
    } else {
      #pragma unroll
      for (int hh = 0; hh < 8; ++hh) sc[hh] = -INFINITY;
    }
    // chunk max per head, xor-butterfly => bit-identical replicated across lanes
    float cm[8];
    #pragma unroll
    for (int hh = 0; hh < 8; ++hh) cm[hh] = sc[hh];
    #pragma unroll
    for (int sft = 32; sft >= 1; sft >>= 1) {
      #pragma unroll
      for (int hh = 0; hh < 8; ++hh)
        cm[hh] = fmaxf(cm[hh], __shfl_xor(cm[hh], sft, 64));
    }
    // online softmax update
    float f[8], pv[8];
    #pragma unroll
    for (int hh = 0; hh < 8; ++hh) {
      float nm = fmaxf(m8[hh], cm[hh]);
      f[hh] = __expf(m8[hh] - nm);       // first chunk: exp(-inf)=0 (state is 0 anyway)
      pv[hh] = __expf(sc[hh] - nm);      // idle lanes: exp(-inf)=0
      m8[hh] = nm;
    }
    if (lane < cnt) {
      float4* pp = (float4*)&pbuf[wid][lane][0];
      pp[0] = make_float4(pv[0], pv[1], pv[2], pv[3]);
      pp[1] = make_float4(pv[4], pv[5], pv[6], pv[7]);
      sbuf[wid][lane] = sid;
    }
    // chunk denominator
    float q[8];
    #pragma unroll
    for (int hh = 0; hh < 8; ++hh) q[hh] = pv[hh];
    #pragma unroll
    for (int sft = 32; sft >= 1; sft >>= 1) {
      #pragma unroll
      for (int hh = 0; hh < 8; ++hh)
        q[hh] += __shfl_xor(q[hh], sft, 64);
    }
    #pragma unroll
    for (int hh = 0; hh < 8; ++hh) den8[hh] = den8[hh]*f[hh] + q[hh];
    msg *= sel8(f[0],f[1],f[2],f[3],f[4],f[5],f[6],f[7], hsel);

    // wave-private LDS: waitcnt is sufficient (no cross-wave sharing, no barrier)
    asm volatile("s_waitcnt lgkmcnt(0)" ::: "memory");

    // message accumulation: lane j owns dim j; coalesced 256B h-row reads
    int e2 = 0;
    for (; e2 + 4 <= cnt; e2 += 4) {
      int s0 = sbuf[wid][e2],   s1 = sbuf[wid][e2+1];
      int s2 = sbuf[wid][e2+2], s3 = sbuf[wid][e2+3];
      float p0 = pbuf[wid][e2][hsel],   p1 = pbuf[wid][e2+1][hsel];
      float p2 = pbuf[wid][e2+2][hsel], p3 = pbuf[wid][e2+3][hsel];
      float h0 = hbuf[(long)s0*DIM + lane];
      float h1 = hbuf[(long)s1*DIM + lane];
      float h2 = hbuf[(long)s2*DIM + lane];
      float h3 = hbuf[(long)s3*DIM + lane];
      msg += h0*p0; msg += h1*p1; msg += h2*p2; msg += h3*p3;
    }
    for (; e2 < cnt; ++e2) {
      int s0 = sbuf[wid][e2];
      float p0 = pbuf[wid][e2][hsel];
      msg += hbuf[(long)s0*DIM + lane] * p0;
    }
  }
  float den = sel8(den8[0],den8[1],den8[2],den8[3],den8[4],den8[5],den8[6],den8[7], hsel);
  den = fmaxf(den, 1e-12f);
  agg[n*DIM + lane] = msg / den;
}

// ---------------- FFN: gelu(agg@w1+b1)@w2+b2, thread per node ----------------
__global__ __launch_bounds__(256) void ffn_kernel(
    const float* __restrict__ agg,
    const float* __restrict__ w1t, const float* __restrict__ b1,
    const float* __restrict__ w2, const float* __restrict__ b2,
    float* __restrict__ out, int n_nodes)
{
  long n = (long)blockIdx.x * blockDim.x + threadIdx.x;
  if (n >= n_nodes) return;
  float xr[64];
  const float4* xp = (const float4*)(agg + n*DIM);
  #pragma unroll
  for (int q = 0; q < 16; ++q) {
    float4 v = xp[q];
    xr[4*q] = v.x; xr[4*q+1] = v.y; xr[4*q+2] = v.z; xr[4*q+3] = v.w;
  }
  float acc[64];
  const float4* b2p = (const float4*)b2;
  #pragma unroll
  for (int q = 0; q < 16; ++q) {
    float4 v = b2p[q];
    acc[4*q] = v.x; acc[4*q+1] = v.y; acc[4*q+2] = v.z; acc[4*q+3] = v.w;
  }
  for (int j = 0; j < HIDDEN; ++j) {
    float hid = b1[j];
    const float4* w1r = (const float4*)(w1t + j*DIM);   // wave-uniform
    #pragma unroll
    for (int q = 0; q < 16; ++q) {
      float4 w = w1r[q];
      hid += xr[4*q]*w.x + xr[4*q+1]*w.y + xr[4*q+2]*w.z + xr[4*q+3]*w.w;
    }
    // exact gelu (matches jax approximate=False)
    hid = 0.5f * hid * (1.0f + erff(hid * 0.70710678118654752f));
    const float4* w2r = (const float4*)(w2 + j*DIM);    // wave-uniform
    #pragma unroll
    for (int q = 0; q < 16; ++q) {
      float4 w = w2r[q];
      acc[4*q]   += hid * w.x;
      acc[4*q+1] += hid * w.y;
      acc[4*q+2] += hid * w.z;
      acc[4*q+3] += hid * w.w;
    }
  }
  float4* op = (float4*)(out + n*DIM);
  #pragma unroll
  for (int q = 0; q < 16; ++q) op[q] = make_float4(acc[4*q], acc[4*q+1], acc[4*q+2], acc[4*q+3]);
}

// ---------------- launch ----------------
extern "C" void kernel_launch(void* const* d_in, const int* in_sizes, int n_in,
                              void* d_out, int out_size, void* d_ws, size_t ws_size,
                              hipStream_t stream)
{
  const float* x         = (const float*)d_in[0];
  const float* edge_feat = (const float*)d_in[1];
  const float* w_in      = (const float*)d_in[2];
  const float* b_in      = (const float*)d_in[3];
  const float* w_edge    = (const float*)d_in[4];
  const float* b_edge    = (const float*)d_in[5];
  const float* w_att_u   = (const float*)d_in[6];
  const float* b_att_u   = (const float*)d_in[7];
  const float* w_att_v   = (const float*)d_in[8];
  const float* w_att_e   = (const float*)d_in[9];
  const float* b_att_e   = (const float*)d_in[10];
  const float* w_ff1     = (const float*)d_in[11];
  const float* b_ff1     = (const float*)d_in[12];
  const float* w_ff2     = (const float*)d_in[13];
  const float* b_ff2     = (const float*)d_in[14];
  const int*   src       = (const int*)d_in[15];
  const int*   dst       = (const int*)d_in[16];
  float* out = (float*)d_out;

  const int n_nodes = in_sizes[0] / DIM;
  const int n_edges = in_sizes[15];

  char* p = (char*)d_ws;
  auto alloc_f = [&](size_t cnt) { float* r = (float*)p; p += ((cnt*4 + 255) & ~(size_t)255); return r; };
  auto alloc_i = [&](size_t cnt) { int* r = (int*)p;   p += ((cnt*4 + 255) & ~(size_t)255); return r; };
  float* Waug  = alloc_f(64*80);
  float* baug  = alloc_f(80);
  float* wcc   = alloc_f(16);
  float* bcc   = alloc_f(8);
  float* w1t   = alloc_f(256*64);
  float* hbuf  = alloc_f((size_t)n_nodes*DIM);
  float* subuf = alloc_f((size_t)n_nodes*8);
  float* svbuf = alloc_f((size_t)n_nodes*8);
  float* aggb  = alloc_f((size_t)n_nodes*DIM);
  int* deg     = alloc_i(n_nodes);
  int* pos     = alloc_i(n_nodes);
  int* counter = alloc_i(64);
  int* offb    = alloc_i(n_nodes);
  int* csr     = alloc_i(n_edges);

  // zero deg, pos, counter in one shot (they are contiguous in the layout)
  hipMemsetAsync(deg, 0, (size_t)((char*)offb - (char*)deg), stream);

  hipLaunchKernelGGL(prep_kernel, dim3(1), dim3(256), 0, stream,
      w_in, b_in, w_edge, b_edge, w_att_u, b_att_u, w_att_v, w_att_e, b_att_e,
      w_ff1, Waug, baug, wcc, bcc, w1t);

  hipLaunchKernelGGL(node_gemm_kernel, dim3((n_nodes+255)/256), dim3(256), 0, stream,
      x, Waug, baug, hbuf, subuf, svbuf, n_nodes);

  hipLaunchKernelGGL(hist_kernel, dim3((n_edges+255)/256), dim3(256), 0, stream,
      dst, deg, n_edges);
  hipLaunchKernelGGL(alloc_kernel, dim3((n_nodes+255)/256), dim3(256), 0, stream,
      deg, offb, counter, n_nodes);
  hipLaunchKernelGGL(scatter_kernel, dim3((n_edges+255)/256), dim3(256), 0, stream,
      dst, offb, pos, csr, n_edges);

  hipLaunchKernelGGL(attn_kernel, dim3((n_nodes+3)/4), dim3(256), 0, stream,
      src, csr, offb, deg, edge_feat, hbuf, subuf, svbuf, wcc, bcc, aggb, n_nodes);

  hipLaunchKernelGGL(ffn_kernel, dim3((n_nodes+255)/256), dim3(256), 0, stream,
      aggb, w1t, b_ff1, w_ff2, b_ff2, out, n_nodes);
}